// Round 7
// baseline (921.882 us; speedup 1.0000x reference)
//
#include <hip/hip_runtime.h>
#include <hip/hip_bf16.h>

#define DIMC   768
#define SEQLEN 4096
#define NBATCH 4
#define KSZ    128
#define UVC    1536
#define XC     3200

typedef __attribute__((ext_vector_type(4))) float f32x4;
typedef __attribute__((ext_vector_type(8))) short bf16x8;
typedef __attribute__((ext_vector_type(4))) short bf16x4;

__device__ __forceinline__ float b2f(short s) {
    unsigned int u = ((unsigned int)(unsigned short)s) << 16;
    return __uint_as_float(u);
}
__device__ __forceinline__ short f2b(float f) {
    __hip_bfloat16 h = __float2bfloat16(f);
    return *reinterpret_cast<short*>(&h);
}

// ---------------------------------------------------------------------------
// Shared GEMM core: C[128x128] tile = A[M][K] (row-major bf16) x Bt[N][K]^T
// 256 threads = 4 waves (2x2), each wave 64x64 = 4x4 fragments of 16x16.
// Single-buffered LDS, BK=32, padded rows (+8 bf16) against bank conflicts.
// Conservative manual staging (no global_load_lds) — correctness-first.
// ---------------------------------------------------------------------------
__device__ __forceinline__ void gemm_core(
    const short* __restrict__ A, const short* __restrict__ Bt,
    int lda, int ldb, int K, long m0, long n0, f32x4 (&acc)[4][4])
{
    __shared__ __attribute__((aligned(16))) short As[128 * 40];
    __shared__ __attribute__((aligned(16))) short Bs[128 * 40];
    const int tid  = threadIdx.x;
    const int lane = tid & 63;
    const int wave = tid >> 6;
    const int wr   = wave >> 1, wc = wave & 1;
    const int l15  = lane & 15, grp = lane >> 4;
    const int srow = tid >> 1;          // 0..127
    const int soff = (tid & 1) * 16;    // 0 or 16 elements

    const long arow = (m0 + srow) * (long)lda;
    const long brow = (n0 + srow) * (long)ldb;

    for (int kk = 0; kk < K; kk += 32) {
        bf16x8 a0 = *(const bf16x8*)(A  + arow + kk + soff);
        bf16x8 a1 = *(const bf16x8*)(A  + arow + kk + soff + 8);
        bf16x8 b0 = *(const bf16x8*)(Bt + brow + kk + soff);
        bf16x8 b1 = *(const bf16x8*)(Bt + brow + kk + soff + 8);
        __syncthreads();   // previous iteration's fragment reads done
        *(bf16x8*)&As[srow * 40 + soff]     = a0;
        *(bf16x8*)&As[srow * 40 + soff + 8] = a1;
        *(bf16x8*)&Bs[srow * 40 + soff]     = b0;
        *(bf16x8*)&Bs[srow * 40 + soff + 8] = b1;
        __syncthreads();
        bf16x8 af[4], bfr[4];
        #pragma unroll
        for (int m = 0; m < 4; m++)
            af[m] = *(const bf16x8*)&As[(wr * 64 + m * 16 + l15) * 40 + grp * 8];
        #pragma unroll
        for (int n = 0; n < 4; n++)
            bfr[n] = *(const bf16x8*)&Bs[(wc * 64 + n * 16 + l15) * 40 + grp * 8];
        #pragma unroll
        for (int m = 0; m < 4; m++)
            #pragma unroll
            for (int n = 0; n < 4; n++)
                acc[m][n] = __builtin_amdgcn_mfma_f32_16x16x32_bf16(
                    af[m], bfr[n], acc[m][n], 0, 0, 0);
    }
}

#define ACC_INIT() \
    f32x4 acc[4][4]; \
    { f32x4 z = {0.f, 0.f, 0.f, 0.f}; \
      _Pragma("unroll") for (int m = 0; m < 4; m++) \
      _Pragma("unroll") for (int n = 0; n < 4; n++) acc[m][n] = z; }

#define EPI_IDX() \
    const int tid = threadIdx.x, lane = tid & 63, wave = tid >> 6; \
    const int wr = wave >> 1, wc = wave & 1, l15 = lane & 15, grp = lane >> 4; \
    (void)tid;

// ---------------- kernel 1: x = silu(h @ Wi + bi), split u/v/qk -------------
__global__ __launch_bounds__(256) void k_gemm_x(
    const short* __restrict__ hb, const short* __restrict__ wit,
    const float* __restrict__ bi,
    short* __restrict__ u, short* __restrict__ v, short* __restrict__ qk)
{
    ACC_INIT();
    long m0 = (long)blockIdx.y * 128;
    long n0 = (long)blockIdx.x * 128;
    gemm_core(hb, wit, DIMC, DIMC, DIMC, m0, n0, acc);
    EPI_IDX();
    #pragma unroll
    for (int m = 0; m < 4; m++)
    #pragma unroll
    for (int n = 0; n < 4; n++)
    #pragma unroll
    for (int r = 0; r < 4; r++) {
        long row = m0 + wr * 64 + m * 16 + grp * 4 + r;
        long col = n0 + wc * 64 + n * 16 + l15;
        float c = acc[m][n][r] + bi[col];
        float s = c / (1.0f + __expf(-c));
        if (col < UVC)            u[row * UVC + col] = f2b(s);
        else if (col < 2 * UVC)   v[row * UVC + (col - UVC)] = f2b(s);
        else                      qk[row * KSZ + (col - 2 * UVC)] = f2b(s);
    }
}

// ------- kernel 2 (per batch): W = relu(q k^T / sqrt(128))^2 / n ------------
__global__ __launch_bounds__(256) void k_gemm_qk(
    const short* __restrict__ q, const short* __restrict__ kmat,
    short* __restrict__ W)
{
    ACC_INIT();
    long m0 = (long)blockIdx.y * 128;
    long n0 = (long)blockIdx.x * 128;
    gemm_core(q, kmat, KSZ, KSZ, KSZ, m0, n0, acc);
    EPI_IDX();
    #pragma unroll
    for (int m = 0; m < 4; m++)
    #pragma unroll
    for (int n = 0; n < 4; n++)
    #pragma unroll
    for (int r = 0; r < 4; r++) {
        long row = m0 + wr * 64 + m * 16 + grp * 4 + r;
        long col = n0 + wc * 64 + n * 16 + l15;
        float s = acc[m][n][r] * 0.08838834764831845f;   // 1/sqrt(128)
        s = fmaxf(s, 0.f);
        s = s * s * (1.0f / SEQLEN);
        W[row * SEQLEN + col] = f2b(s);
    }
}

// ------- kernel 3 (per batch): t = u * (W @ v) ------------------------------
__global__ __launch_bounds__(256) void k_gemm_wv(
    const short* __restrict__ W, const short* __restrict__ vt,
    const short* __restrict__ u, short* __restrict__ t)
{
    ACC_INIT();
    long m0 = (long)blockIdx.y * 128;
    long n0 = (long)blockIdx.x * 128;
    gemm_core(W, vt, SEQLEN, SEQLEN, SEQLEN, m0, n0, acc);
    EPI_IDX();
    #pragma unroll
    for (int m = 0; m < 4; m++)
    #pragma unroll
    for (int n = 0; n < 4; n++)
    #pragma unroll
    for (int r = 0; r < 4; r++) {
        long row = m0 + wr * 64 + m * 16 + grp * 4 + r;
        long col = n0 + wc * 64 + n * 16 + l15;
        float val = acc[m][n][r] * b2f(u[row * UVC + col]);
        t[row * UVC + col] = f2b(val);
    }
}

// ---------------- kernel 4: o = t @ Wo + bo + h  (fp32 -> d_out) ------------
__global__ __launch_bounds__(256) void k_gemm_out(
    const short* __restrict__ t, const short* __restrict__ wot,
    const float* __restrict__ bo, const float* __restrict__ h,
    float* __restrict__ o)
{
    ACC_INIT();
    long m0 = (long)blockIdx.y * 128;
    long n0 = (long)blockIdx.x * 128;
    gemm_core(t, wot, UVC, UVC, UVC, m0, n0, acc);
    EPI_IDX();
    #pragma unroll
    for (int m = 0; m < 4; m++)
    #pragma unroll
    for (int n = 0; n < 4; n++)
    #pragma unroll
    for (int r = 0; r < 4; r++) {
        long row = m0 + wr * 64 + m * 16 + grp * 4 + r;
        long col = n0 + wc * 64 + n * 16 + l15;
        o[row * DIMC + col] = acc[m][n][r] + bo[col] + h[row * DIMC + col];
    }
}

// ---------------- helpers ----------------------------------------------------
__global__ void k_f2b(const float* __restrict__ in, short* __restrict__ out, long n)
{
    long i = ((long)blockIdx.x * blockDim.x + threadIdx.x) * 4;
    if (i >= n) return;
    float4 f = *(const float4*)(in + i);
    bf16x4 o4 = { f2b(f.x), f2b(f.y), f2b(f.z), f2b(f.w) };
    *(bf16x4*)(out + i) = o4;
}

// out[C][R] (bf16) = transpose of in[R][C] (fp32)
__global__ void k_transpose_f2b(const float* __restrict__ in, short* __restrict__ out,
                                int R, int C)
{
    long idx = (long)blockIdx.x * 256 + threadIdx.x;
    int oc   = (int)(idx % R);
    int orow = (int)(idx / R);
    out[idx] = f2b(in[(long)oc * C + orow]);
}

// q = rope(qk*qg+qb), k = rope(qk*kg+kb)
__global__ void k_rope(const short* __restrict__ qk,
    const float* __restrict__ qg, const float* __restrict__ qb,
    const float* __restrict__ kg, const float* __restrict__ kb,
    short* __restrict__ qo, short* __restrict__ ko)
{
    int row = blockIdx.x;
    int j = threadIdx.x;      // 0..127
    int i = j & 63;
    int pos = row & (SEQLEN - 1);
    float x1 = b2f(qk[(long)row * KSZ + 2 * i]);
    float x2 = b2f(qk[(long)row * KSZ + 2 * i + 1]);
    // mirror numpy: omega = 1/10000^(i/64) in fp32, ang = pos*omega in fp32
    float omega = powf(10000.0f, -(float)i * (1.0f / 64.0f));
    float ang = (float)pos * omega;
    float s, c;
    sincosf(ang, &s, &c);
    float a1q = x1 * qg[2 * i] + qb[2 * i], a2q = x2 * qg[2 * i + 1] + qb[2 * i + 1];
    float a1k = x1 * kg[2 * i] + kb[2 * i], a2k = x2 * kg[2 * i + 1] + kb[2 * i + 1];
    float qv = (j < 64) ? (a1q * c - a2q * s) : (a1q * s + a2q * c);
    float kv = (j < 64) ? (a1k * c - a2k * s) : (a1k * s + a2k * c);
    qo[(long)row * KSZ + j] = f2b(qv);
    ko[(long)row * KSZ + j] = f2b(kv);
}

// vt[d][n] = v[n][d] for one batch (tiled 64x64 transpose, bf16)
__global__ __launch_bounds__(256) void k_vtrans(const short* __restrict__ v,
                                                short* __restrict__ vt)
{
    __shared__ __attribute__((aligned(16))) short tile[64][68];
    int ni = blockIdx.x, di = blockIdx.y;
    int t = threadIdx.x;
    int tr = t >> 4;
    int tc = (t & 15) * 4;
    const short* src = v + ((long)ni * 64) * UVC + (long)di * 64;
    #pragma unroll
    for (int i2 = 0; i2 < 4; i2++) {
        int r = tr + 16 * i2;
        *(bf16x4*)&tile[r][tc] = *(const bf16x4*)&src[(long)r * UVC + tc];
    }
    __syncthreads();
    short* dst = vt + (long)di * 64 * SEQLEN + (long)ni * 64;
    #pragma unroll
    for (int i2 = 0; i2 < 4; i2++) {
        int r = tr + 16 * i2;   // d_local
        bf16x4 pk;
        pk[0] = tile[tc + 0][r]; pk[1] = tile[tc + 1][r];
        pk[2] = tile[tc + 2][r]; pk[3] = tile[tc + 3][r];
        *(bf16x4*)&dst[(long)r * SEQLEN + tc] = pk;
    }
}

// RMS norm over last dim (768), IN PLACE on d_out (no restrict: aliased)
__global__ __launch_bounds__(256) void k_rms(float* o)
{
    int row = blockIdx.x;
    int t = threadIdx.x;
    float* orow = o + (long)row * DIMC;
    float v0 = orow[t], v1 = orow[t + 256], v2 = orow[t + 512];
    float ss = v0 * v0 + v1 * v1 + v2 * v2;
    #pragma unroll
    for (int off = 32; off > 0; off >>= 1) ss += __shfl_down(ss, off, 64);
    __shared__ float red[4];
    if ((t & 63) == 0) red[t >> 6] = ss;
    __syncthreads();
    float tot = red[0] + red[1] + red[2] + red[3];
    float scale = rsqrtf(tot * (1.0f / DIMC) + 1e-12f);
    orow[t] = v0 * scale; orow[t + 256] = v1 * scale; orow[t + 512] = v2 * scale;
}

// ---------------------------------------------------------------------------
extern "C" void kernel_launch(void* const* d_in, const int* in_sizes, int n_in,
                              void* d_out, int out_size, void* d_ws, size_t ws_size,
                              hipStream_t stream)
{
    const float* h  = (const float*)d_in[0];
    const float* Wi = (const float*)d_in[1];
    const float* bi = (const float*)d_in[2];
    const float* Wo = (const float*)d_in[3];
    const float* bo = (const float*)d_in[4];
    const float* qg = (const float*)d_in[5];
    const float* qb = (const float*)d_in[6];
    const float* kg = (const float*)d_in[7];
    const float* kb = (const float*)d_in[8];

    // Workspace layout (compact, 191,823,872 B total)
    char* ws = (char*)d_ws;
    short* hb   = (short*)(ws + 0L);           // 25,165,824  bf16 h
    short* wit  = (short*)(ws + 25165824L);    //  4,915,200  Wi^T bf16 [3200][768]
    short* wot  = (short*)(ws + 30081024L);    //  2,359,296  Wo^T bf16 [768][1536]
    short* u    = (short*)(ws + 32440320L);    // 50,331,648
    short* v    = (short*)(ws + 82771968L);    // 50,331,648  (aliased as t per batch)
    short* qk   = (short*)(ws + 133103616L);   //  4,194,304
    short* qbuf = (short*)(ws + 137297920L);   //  4,194,304
    short* kbuf = (short*)(ws + 141492224L);   //  4,194,304
    short* vt   = (short*)(ws + 145686528L);   // 12,582,912  V^T one batch [1536][4096]
    short* W    = (short*)(ws + 158269440L);   // 33,554,432  W one batch [4096][4096]
    short* tbuf = v;   // t[b] overwrites v[b] after k_vtrans(b) consumed it

    if (ws_size < 191823872UL) return;  // diagnostic: absmax==max|ref| signature

    long nh = (long)NBATCH * SEQLEN * DIMC;    // 12,582,912

    k_f2b<<<dim3((unsigned)(nh / 4 / 256)), 256, 0, stream>>>(h, hb, nh);
    k_transpose_f2b<<<dim3((768 * 3200) / 256), 256, 0, stream>>>(Wi, wit, 768, 3200);
    k_transpose_f2b<<<dim3((1536 * 768) / 256), 256, 0, stream>>>(Wo, wot, 1536, 768);

    k_gemm_x<<<dim3(XC / 128, (NBATCH * SEQLEN) / 128), 256, 0, stream>>>(
        hb, wit, bi, u, v, qk);

    k_rope<<<dim3(NBATCH * SEQLEN), 128, 0, stream>>>(qk, qg, qb, kg, kb, qbuf, kbuf);

    for (int b = 0; b < NBATCH; ++b) {
        const long so = (long)b * SEQLEN;
        k_vtrans<<<dim3(SEQLEN / 64, UVC / 64), 256, 0, stream>>>(
            v + so * UVC, vt);
        k_gemm_qk<<<dim3(SEQLEN / 128, SEQLEN / 128), 256, 0, stream>>>(
            qbuf + so * KSZ, kbuf + so * KSZ, W);
        k_gemm_wv<<<dim3(UVC / 128, SEQLEN / 128), 256, 0, stream>>>(
            W, vt, u + so * UVC, tbuf + so * UVC);
    }

    k_gemm_out<<<dim3(DIMC / 128, (NBATCH * SEQLEN) / 128), 256, 0, stream>>>(
        tbuf, wot, bo, h, (float*)d_out);

    k_rms<<<dim3(NBATCH * SEQLEN), 256, 0, stream>>>((float*)d_out);
}

// Round 14
// 820.859 us; speedup vs baseline: 1.1231x; 1.1231x over previous
//
#include <hip/hip_runtime.h>
#include <hip/hip_bf16.h>

#define DIMC   768
#define SEQLEN 4096
#define NBATCH 4
#define KSZ    128
#define UVC    1536
#define XC     3200

typedef __attribute__((ext_vector_type(4))) float f32x4;
typedef __attribute__((ext_vector_type(8))) short bf16x8;
typedef __attribute__((ext_vector_type(4))) short bf16x4;

__device__ __forceinline__ float b2f(short s) {
    unsigned int u = ((unsigned int)(unsigned short)s) << 16;
    return __uint_as_float(u);
}
__device__ __forceinline__ short f2b(float f) {
    __hip_bfloat16 h = __float2bfloat16(f);
    return *reinterpret_cast<short*>(&h);
}

// async global->LDS, 16B per lane. LDS dest = wave-uniform base + lane*16.
__device__ __forceinline__ void gload_lds16(const short* g, short* l) {
    __builtin_amdgcn_global_load_lds(
        (const __attribute__((address_space(1))) void*)g,
        (__attribute__((address_space(3))) void*)l, 16, 0, 0);
}

// ---------------------------------------------------------------------------
// GEMM core (m97 structure): C[128x128] = A[M][K] (row-major bf16) x Bt[N][K]^T
// 256 threads = 4 waves (2x2), each wave owns a 64x64 output = 4x4 frags 16x16.
// BK=32. Linear LDS [128][32] (64 B rows), staged via global_load_lds width=16:
// 8 chunks x 1024 B per operand, wave w stages chunks {2w,2w+1} of A and B.
// chunk c, lane l: row=16c+(l>>2), col=(l&3)*8 elems == LDS elem lane*8 (linear
// dest + linear source, G21). __syncthreads drains vmcnt(0) before s_barrier.
// ---------------------------------------------------------------------------
__device__ __forceinline__ void gemm_core(
    const short* __restrict__ A, const short* __restrict__ Bt,
    int lda, int ldb, int K, long m0, long n0, f32x4 (&acc)[4][4])
{
    __shared__ __attribute__((aligned(16))) short As[128 * 32];
    __shared__ __attribute__((aligned(16))) short Bs[128 * 32];
    const int tid  = threadIdx.x;
    const int lane = tid & 63;
    const int wave = tid >> 6;
    const int wr   = wave >> 1, wc = wave & 1;
    const int l15  = lane & 15, grp = lane >> 4;

    const int c0 = 2 * wave, c1 = 2 * wave + 1;
    const int lr = lane >> 2;          // row within 16-row chunk
    const int lb = (lane & 3) * 8;     // element offset within 32-elem row

    const short* ga0 = A  + (m0 + c0 * 16 + lr) * (long)lda + lb;
    const short* ga1 = A  + (m0 + c1 * 16 + lr) * (long)lda + lb;
    const short* gb0 = Bt + (n0 + c0 * 16 + lr) * (long)ldb + lb;
    const short* gb1 = Bt + (n0 + c1 * 16 + lr) * (long)ldb + lb;

    short* la0 = As + c0 * 512;
    short* la1 = As + c1 * 512;
    short* lB0 = Bs + c0 * 512;
    short* lB1 = Bs + c1 * 512;

    for (int kk = 0; kk < K; kk += 32) {
        __syncthreads();               // prior frag reads done before overwrite
        gload_lds16(ga0 + kk, la0);
        gload_lds16(ga1 + kk, la1);
        gload_lds16(gb0 + kk, lB0);
        gload_lds16(gb1 + kk, lB1);
        __syncthreads();               // drains vmcnt(0): tiles resident
        bf16x8 af[4], bfr[4];
        #pragma unroll
        for (int m = 0; m < 4; m++)
            af[m] = *(const bf16x8*)&As[(wr * 64 + m * 16 + l15) * 32 + grp * 8];
        #pragma unroll
        for (int n = 0; n < 4; n++)
            bfr[n] = *(const bf16x8*)&Bs[(wc * 64 + n * 16 + l15) * 32 + grp * 8];
        #pragma unroll
        for (int m = 0; m < 4; m++)
            #pragma unroll
            for (int n = 0; n < 4; n++)
                acc[m][n] = __builtin_amdgcn_mfma_f32_16x16x32_bf16(
                    af[m], bfr[n], acc[m][n], 0, 0, 0);
    }
}

#define ACC_INIT() \
    f32x4 acc[4][4]; \
    { f32x4 z = {0.f, 0.f, 0.f, 0.f}; \
      _Pragma("unroll") for (int m = 0; m < 4; m++) \
      _Pragma("unroll") for (int n = 0; n < 4; n++) acc[m][n] = z; }

#define EPI_IDX() \
    const int tid = threadIdx.x, lane = tid & 63, wave = tid >> 6; \
    const int wr = wave >> 1, wc = wave & 1, l15 = lane & 15, grp = lane >> 4; \
    (void)tid;

// ---------------- kernel 1: x = silu(h @ Wi + bi), split u/v/qk -------------
__global__ __launch_bounds__(256) void k_gemm_x(
    const short* __restrict__ hb, const short* __restrict__ wit,
    const float* __restrict__ bi,
    short* __restrict__ u, short* __restrict__ v, short* __restrict__ qk)
{
    ACC_INIT();
    long m0 = (long)blockIdx.y * 128;
    long n0 = (long)blockIdx.x * 128;
    gemm_core(hb, wit, DIMC, DIMC, DIMC, m0, n0, acc);
    EPI_IDX();
    #pragma unroll
    for (int m = 0; m < 4; m++)
    #pragma unroll
    for (int n = 0; n < 4; n++)
    #pragma unroll
    for (int r = 0; r < 4; r++) {
        long row = m0 + wr * 64 + m * 16 + grp * 4 + r;
        long col = n0 + wc * 64 + n * 16 + l15;
        float c = acc[m][n][r] + bi[col];
        float s = c / (1.0f + __expf(-c));
        if (col < UVC)            u[row * UVC + col] = f2b(s);
        else if (col < 2 * UVC)   v[row * UVC + (col - UVC)] = f2b(s);
        else                      qk[row * KSZ + (col - 2 * UVC)] = f2b(s);
    }
}

// ------- kernel 2 (per batch): W = relu(q k^T / sqrt(128))^2 / n ------------
__global__ __launch_bounds__(256) void k_gemm_qk(
    const short* __restrict__ q, const short* __restrict__ kmat,
    short* __restrict__ W)
{
    ACC_INIT();
    long m0 = (long)blockIdx.y * 128;
    long n0 = (long)blockIdx.x * 128;
    gemm_core(q, kmat, KSZ, KSZ, KSZ, m0, n0, acc);
    EPI_IDX();
    #pragma unroll
    for (int m = 0; m < 4; m++)
    #pragma unroll
    for (int n = 0; n < 4; n++)
    #pragma unroll
    for (int r = 0; r < 4; r++) {
        long row = m0 + wr * 64 + m * 16 + grp * 4 + r;
        long col = n0 + wc * 64 + n * 16 + l15;
        float s = acc[m][n][r] * 0.08838834764831845f;   // 1/sqrt(128)
        s = fmaxf(s, 0.f);
        s = s * s * (1.0f / SEQLEN);
        W[row * SEQLEN + col] = f2b(s);
    }
}

// ------- kernel 3 (per batch): t = u * (W @ v) ------------------------------
__global__ __launch_bounds__(256) void k_gemm_wv(
    const short* __restrict__ W, const short* __restrict__ vt,
    const short* __restrict__ u, short* __restrict__ t)
{
    ACC_INIT();
    long m0 = (long)blockIdx.y * 128;
    long n0 = (long)blockIdx.x * 128;
    gemm_core(W, vt, SEQLEN, SEQLEN, SEQLEN, m0, n0, acc);
    EPI_IDX();
    #pragma unroll
    for (int m = 0; m < 4; m++)
    #pragma unroll
    for (int n = 0; n < 4; n++)
    #pragma unroll
    for (int r = 0; r < 4; r++) {
        long row = m0 + wr * 64 + m * 16 + grp * 4 + r;
        long col = n0 + wc * 64 + n * 16 + l15;
        float val = acc[m][n][r] * b2f(u[row * UVC + col]);
        t[row * UVC + col] = f2b(val);
    }
}

// ---------------- kernel 4: o = t @ Wo + bo + h  (fp32 -> d_out) ------------
__global__ __launch_bounds__(256) void k_gemm_out(
    const short* __restrict__ t, const short* __restrict__ wot,
    const float* __restrict__ bo, const float* __restrict__ h,
    float* __restrict__ o)
{
    ACC_INIT();
    long m0 = (long)blockIdx.y * 128;
    long n0 = (long)blockIdx.x * 128;
    gemm_core(t, wot, UVC, UVC, UVC, m0, n0, acc);
    EPI_IDX();
    #pragma unroll
    for (int m = 0; m < 4; m++)
    #pragma unroll
    for (int n = 0; n < 4; n++)
    #pragma unroll
    for (int r = 0; r < 4; r++) {
        long row = m0 + wr * 64 + m * 16 + grp * 4 + r;
        long col = n0 + wc * 64 + n * 16 + l15;
        o[row * DIMC + col] = acc[m][n][r] + bo[col] + h[row * DIMC + col];
    }
}

// ---------------- helpers ----------------------------------------------------
__global__ void k_f2b(const float* __restrict__ in, short* __restrict__ out, long n)
{
    long i = ((long)blockIdx.x * blockDim.x + threadIdx.x) * 4;
    if (i >= n) return;
    float4 f = *(const float4*)(in + i);
    bf16x4 o4 = { f2b(f.x), f2b(f.y), f2b(f.z), f2b(f.w) };
    *(bf16x4*)(out + i) = o4;
}

// out[C][R] (bf16) = transpose of in[R][C] (fp32)
__global__ void k_transpose_f2b(const float* __restrict__ in, short* __restrict__ out,
                                int R, int C)
{
    long idx = (long)blockIdx.x * 256 + threadIdx.x;
    int oc   = (int)(idx % R);
    int orow = (int)(idx / R);
    out[idx] = f2b(in[(long)oc * C + orow]);
}

// q = rope(qk*qg+qb), k = rope(qk*kg+kb)
__global__ void k_rope(const short* __restrict__ qk,
    const float* __restrict__ qg, const float* __restrict__ qb,
    const float* __restrict__ kg, const float* __restrict__ kb,
    short* __restrict__ qo, short* __restrict__ ko)
{
    int row = blockIdx.x;
    int j = threadIdx.x;      // 0..127
    int i = j & 63;
    int pos = row & (SEQLEN - 1);
    float x1 = b2f(qk[(long)row * KSZ + 2 * i]);
    float x2 = b2f(qk[(long)row * KSZ + 2 * i + 1]);
    // mirror numpy: omega = 1/10000^(i/64) in fp32, ang = pos*omega in fp32
    float omega = powf(10000.0f, -(float)i * (1.0f / 64.0f));
    float ang = (float)pos * omega;
    float s, c;
    sincosf(ang, &s, &c);
    float a1q = x1 * qg[2 * i] + qb[2 * i], a2q = x2 * qg[2 * i + 1] + qb[2 * i + 1];
    float a1k = x1 * kg[2 * i] + kb[2 * i], a2k = x2 * kg[2 * i + 1] + kb[2 * i + 1];
    float qv = (j < 64) ? (a1q * c - a2q * s) : (a1q * s + a2q * c);
    float kv = (j < 64) ? (a1k * c - a2k * s) : (a1k * s + a2k * c);
    qo[(long)row * KSZ + j] = f2b(qv);
    ko[(long)row * KSZ + j] = f2b(kv);
}

// vt[d][n] = v[n][d] for one batch (tiled 64x64 transpose, bf16)
__global__ __launch_bounds__(256) void k_vtrans(const short* __restrict__ v,
                                                short* __restrict__ vt)
{
    __shared__ __attribute__((aligned(16))) short tile[64][68];
    int ni = blockIdx.x, di = blockIdx.y;
    int t = threadIdx.x;
    int tr = t >> 4;
    int tc = (t & 15) * 4;
    const short* src = v + ((long)ni * 64) * UVC + (long)di * 64;
    #pragma unroll
    for (int i2 = 0; i2 < 4; i2++) {
        int r = tr + 16 * i2;
        *(bf16x4*)&tile[r][tc] = *(const bf16x4*)&src[(long)r * UVC + tc];
    }
    __syncthreads();
    short* dst = vt + (long)di * 64 * SEQLEN + (long)ni * 64;
    #pragma unroll
    for (int i2 = 0; i2 < 4; i2++) {
        int r = tr + 16 * i2;   // d_local
        bf16x4 pk;
        pk[0] = tile[tc + 0][r]; pk[1] = tile[tc + 1][r];
        pk[2] = tile[tc + 2][r]; pk[3] = tile[tc + 3][r];
        *(bf16x4*)&dst[(long)r * SEQLEN + tc] = pk;
    }
}

// RMS norm over last dim (768), IN PLACE on d_out (no restrict: aliased)
__global__ __launch_bounds__(256) void k_rms(float* o)
{
    int row = blockIdx.x;
    int t = threadIdx.x;
    float* orow = o + (long)row * DIMC;
    float v0 = orow[t], v1 = orow[t + 256], v2 = orow[t + 512];
    float ss = v0 * v0 + v1 * v1 + v2 * v2;
    #pragma unroll
    for (int off = 32; off > 0; off >>= 1) ss += __shfl_down(ss, off, 64);
    __shared__ float red[4];
    if ((t & 63) == 0) red[t >> 6] = ss;
    __syncthreads();
    float tot = red[0] + red[1] + red[2] + red[3];
    float scale = rsqrtf(tot * (1.0f / DIMC) + 1e-12f);
    orow[t] = v0 * scale; orow[t + 256] = v1 * scale; orow[t + 512] = v2 * scale;
}

// ---------------------------------------------------------------------------
extern "C" void kernel_launch(void* const* d_in, const int* in_sizes, int n_in,
                              void* d_out, int out_size, void* d_ws, size_t ws_size,
                              hipStream_t stream)
{
    const float* h  = (const float*)d_in[0];
    const float* Wi = (const float*)d_in[1];
    const float* bi = (const float*)d_in[2];
    const float* Wo = (const float*)d_in[3];
    const float* bo = (const float*)d_in[4];
    const float* qg = (const float*)d_in[5];
    const float* qb = (const float*)d_in[6];
    const float* kg = (const float*)d_in[7];
    const float* kb = (const float*)d_in[8];

    // Workspace layout (compact, 191,823,872 B total)
    char* ws = (char*)d_ws;
    short* hb   = (short*)(ws + 0L);           // 25,165,824  bf16 h
    short* wit  = (short*)(ws + 25165824L);    //  4,915,200  Wi^T bf16 [3200][768]
    short* wot  = (short*)(ws + 30081024L);    //  2,359,296  Wo^T bf16 [768][1536]
    short* u    = (short*)(ws + 32440320L);    // 50,331,648
    short* v    = (short*)(ws + 82771968L);    // 50,331,648  (aliased as t per batch)
    short* qk   = (short*)(ws + 133103616L);   //  4,194,304
    short* qbuf = (short*)(ws + 137297920L);   //  4,194,304
    short* kbuf = (short*)(ws + 141492224L);   //  4,194,304
    short* vt   = (short*)(ws + 145686528L);   // 12,582,912  V^T one batch [1536][4096]
    short* W    = (short*)(ws + 158269440L);   // 33,554,432  W one batch [4096][4096]
    short* tbuf = v;   // t[b] overwrites v[b] after k_vtrans(b) consumed it

    if (ws_size < 191823872UL) return;  // diagnostic: absmax==max|ref| signature

    long nh = (long)NBATCH * SEQLEN * DIMC;    // 12,582,912

    k_f2b<<<dim3((unsigned)(nh / 4 / 256)), 256, 0, stream>>>(h, hb, nh);
    k_transpose_f2b<<<dim3((768 * 3200) / 256), 256, 0, stream>>>(Wi, wit, 768, 3200);
    k_transpose_f2b<<<dim3((1536 * 768) / 256), 256, 0, stream>>>(Wo, wot, 1536, 768);

    k_gemm_x<<<dim3(XC / 128, (NBATCH * SEQLEN) / 128), 256, 0, stream>>>(
        hb, wit, bi, u, v, qk);

    k_rope<<<dim3(NBATCH * SEQLEN), 128, 0, stream>>>(qk, qg, qb, kg, kb, qbuf, kbuf);

    for (int b = 0; b < NBATCH; ++b) {
        const long so = (long)b * SEQLEN;
        k_vtrans<<<dim3(SEQLEN / 64, UVC / 64), 256, 0, stream>>>(
            v + so * UVC, vt);
        k_gemm_qk<<<dim3(SEQLEN / 128, SEQLEN / 128), 256, 0, stream>>>(
            qbuf + so * KSZ, kbuf + so * KSZ, W);
        k_gemm_wv<<<dim3(UVC / 128, SEQLEN / 128), 256, 0, stream>>>(
            W, vt, u + so * UVC, tbuf + so * UVC);
    }

    k_gemm_out<<<dim3(DIMC / 128, (NBATCH * SEQLEN) / 128), 256, 0, stream>>>(
        tbuf, wot, bo, h, (float*)d_out);

    k_rms<<<dim3(NBATCH * SEQLEN), 256, 0, stream>>>((float*)d_out);
}